// Round 4
// baseline (558.238 us; speedup 1.0000x reference)
//
#include <hip/hip_runtime.h>
#include <hip/hip_bf16.h>
#include <math.h>

// Problem constants (n=2, t=12, h=w=96, c=64)
#define NN 2
#define TT 12
#define HH 96
#define WW 96
#define CC 64
#define H4 24
#define W4 24
#define FL 1024   // feat_len = c*16
#define FN 576    // H4*W4

typedef short short8 __attribute__((ext_vector_type(8)));
typedef float f32x4 __attribute__((ext_vector_type(4)));

__device__ __forceinline__ float u2f(unsigned short u){
  unsigned int x = ((unsigned int)u)<<16; float f; __builtin_memcpy(&f,&x,4); return f;
}
__device__ __forceinline__ unsigned short f2u(float f){
  __hip_bfloat16 b = __float2bfloat16(f); unsigned short u; __builtin_memcpy(&u,&b,2); return u;
}

// ---------------- K0: nearest-neighbor source map -------------------------
__global__ void k_map(const float* __restrict__ loc, int* __restrict__ smap){
  int i = blockIdx.x*256 + threadIdx.x;
  if (i >= NN*TT*FN) return;
  int nt = i / FN, pix = i % FN;
  int ni = nt / TT, ti = nt % TT;
  const float* lp = loc + ((size_t)ni*(2*TT) + 2*ti)*FN + pix;
  float vx = lp[0];
  float vy = lp[FN];
  // EXACT replication of reference f32 arithmetic:
  float gx = (2.0f*vx)/23.0f - 1.0f;
  float gy = (2.0f*vy)/23.0f - 1.0f;
  float x = ((gx + 1.0f)*0.5f)*23.0f;
  float y = ((gy + 1.0f)*0.5f)*23.0f;
  int xi = (int)rintf(x);
  int yi = (int)rintf(y);
  bool valid = (xi>=0)&&(xi<W4)&&(yi>=0)&&(yi<H4);
  smap[i] = valid ? (yi*W4+xi) : -1;
}

// ---------------- K1: per-source-pixel L2 norms (coalesced) ---------------
__global__ void k_part(const float* __restrict__ idxf, float* __restrict__ part){
  int blk = blockIdx.x;           // nt*16 + chunk
  int nt = blk >> 4, ch0 = (blk & 15)*64;
  int pix = threadIdx.x;          // 576 threads
  const float* p = idxf + ((size_t)nt*FL + ch0)*FN + pix;
  float s = 0.f;
  for (int c=0;c<64;c++){ float v = p[(size_t)c*FN]; s += v*v; }
  part[(size_t)blk*FN + pix] = s;
}
__global__ void k_norm(const float* __restrict__ part, float* __restrict__ nrm){
  int i = blockIdx.x*256+threadIdx.x;
  if (i>=NN*TT*FN) return;
  int nt = i/FN, pix = i%FN;
  float s=0.f;
  for (int c=0;c<16;c++) s += part[(size_t)(nt*16+c)*FN + pix];
  nrm[i] = sqrtf(s);
}

// ---------------- K2: normalized unfolded query cf[n][l][1024] ------------
__global__ void k_cf(const float* __restrict__ curr, float* __restrict__ cf){
  int blk = blockIdx.x;           // n*576 + l
  int ni = blk/FN, l = blk%FN;
  int by = l/W4, bx = l%W4;
  int tid = threadIdx.x;
  int ci = tid>>2, sy = tid&3;
  const float* p = curr + (((size_t)ni*CC+ci)*HH + by*4+sy)*WW + bx*4;
  float4 v = *(const float4*)p;
  float s = v.x*v.x+v.y*v.y+v.z*v.z+v.w*v.w;
  __shared__ float red[256];
  red[tid]=s; __syncthreads();
  for(int o=128;o>0;o>>=1){ if(tid<o) red[tid]+=red[tid+o]; __syncthreads(); }
  float r = 1.0f/fmaxf(sqrtf(red[0]),1e-12f);
  float4 o4 = make_float4(v.x*r, v.y*r, v.z*r, v.w*r);
  ((float4*)(cf + (size_t)blk*FL))[tid] = o4;
}

// ---------------- K3a: transpose+normalize idxf -> idxT [nt][pix][1024] ---
__global__ __launch_bounds__(256) void k_tr_idx(const float* __restrict__ idxf,
    const float* __restrict__ nrm, float* __restrict__ idxT){
  int b = blockIdx.x;             // ((nt*9 + pixt)*16 + cht)
  int cht = b & 15; int b2 = b >> 4;
  int pixt = b2 % 9; int nt = b2 / 9;
  int tid = threadIdx.x;
  __shared__ float t[64][65];
  #pragma unroll
  for (int r=0; r<16; ++r){
    int ch_l = r*4 + (tid>>6), pix_l = tid & 63;
    t[ch_l][pix_l] = idxf[((size_t)nt*FL + cht*64 + ch_l)*FN + pixt*64 + pix_l];
  }
  __syncthreads();
  #pragma unroll
  for (int r=0; r<16; ++r){
    int pix_l = r*4 + (tid>>6), ch_l = tid & 63;
    int gpix = pixt*64 + pix_l;
    float inv = 1.0f/fmaxf(nrm[nt*FN + gpix], 1e-12f);
    idxT[((size_t)nt*FN + gpix)*FL + cht*64 + ch_l] = t[ch_l][pix_l]*inv;
  }
}

// ---------------- K3b: transpose s1/s2/s3 -> bf16 sT [tens][nt][pix][1024]-
__global__ __launch_bounds__(256) void k_tr_s(const float* __restrict__ s1,
    const float* __restrict__ s2, const float* __restrict__ s3,
    unsigned short* __restrict__ sT){
  int b = blockIdx.x;             // tens*3456 + ((nt*9+pixt)*16+cht)
  int tens = b / 3456; int bb = b % 3456;
  int cht = bb & 15; int b2 = bb >> 4;
  int pixt = b2 % 9; int nt = b2 / 9;
  const float* src = (tens==0)? s1 : (tens==1)? s2 : s3;
  int tid = threadIdx.x;
  __shared__ float t[64][65];
  #pragma unroll
  for (int r=0; r<16; ++r){
    int ch_l = r*4 + (tid>>6), pix_l = tid & 63;
    t[ch_l][pix_l] = src[((size_t)nt*FL + cht*64 + ch_l)*FN + pixt*64 + pix_l];
  }
  __syncthreads();
  #pragma unroll
  for (int r=0; r<16; ++r){
    int pix_l = r*4 + (tid>>6), ch_l = tid & 63;
    int gpix = pixt*64 + pix_l;
    sT[((size_t)(tens*NN*TT + nt)*FN + gpix)*FL + cht*64 + ch_l] = f2u(t[ch_l][pix_l]);
  }
}

// ---------------- K3c: prepack fusion weights in MFMA B-fragment order ----
__global__ void k_wpack(const float* __restrict__ fw, unsigned short* __restrict__ wp){
  int idx = blockIdx.x*256 + threadIdx.x;
  if (idx >= 9*6*4*64*8) return;
  int j = idx & 7; int t2 = idx >> 3;
  int L = t2 & 63; int t3 = t2 >> 6;
  int ntl = t3 & 3; int t4 = t3 >> 2;
  int kc = t4 % 6; int tap = t4 / 6;
  int dy = tap/3, dx = tap%3;
  int n = ntl*16 + (L & 15);
  int quad = L >> 4;
  int k = kc*32 + quad*8 + j;     // ci in [0,192)
  wp[idx] = f2u(fw[((size_t)n*192 + k)*9 + dy*3 + dx]);
}

// ---------------- K4: fused offset network -> grid2 (pixel coords) --------
// 2 output rows per block; XCD-swizzled so all blocks of one b share blockIdx%8
__global__ __launch_bounds__(256) void k_offnet(
    const float* __restrict__ cf, const float* __restrict__ idxT,
    const int* __restrict__ smap,
    const float* __restrict__ dw_w, const float* __restrict__ dw_b,
    const float* __restrict__ ln_w, const float* __restrict__ ln_b,
    const float* __restrict__ pw_w, float* __restrict__ grid2){
  int i0 = blockIdx.x;            // 1152 = 96 b x 12 ybands
  int xcd = i0 & 7; int kk = i0 >> 3;   // kk in [0,144)
  int b = (kk/12)*8 + xcd;              // [0,96): all 12 bands of b on one XCD
  int y0 = 2*(kk%12);
  int i = threadIdx.x;
  float wA[25], wB[25];
  const float* wp = dw_w + (size_t)i*50;
  #pragma unroll
  for(int k=0;k<25;k++){ wA[k]=wp[k]; wB[k]=wp[25+k]; }
  const float* src; int choff; const int* smrow;
  if (i < 128){                   // q part: tile ordering (rep, n, g)
    int n2 = (b>>2)&1, g2 = b&3;
    src = cf + (size_t)n2*FN*FL;
    choff = g2*256 + 2*i;
    smrow = nullptr;
  } else {                        // k part: ordering (n, t, g)
    int nk = b/48, tik = (b>>2)%12, gk = b&3;
    int nt = nk*TT + tik;
    src = idxT + (size_t)nt*FN*FL;
    choff = gk*256 + 2*(i-128);
    smrow = smap + nt*FN;
  }
  float acc[2][24];
  #pragma unroll
  for(int x=0;x<24;x++){ acc[0][x]=0.f; acc[1][x]=0.f; }
  for(int r = y0-2; r <= y0+3; ++r){
    if (r < 0 || r >= H4) continue;
    int dy0 = r - y0 + 2;         // [0,6)
    int dy1 = dy0 - 1;            // [-1,5)
    bool u0 = (dy0 < 5), u1 = (dy1 >= 0);
    #pragma unroll
    for(int xx=0; xx<24; ++xx){
      int pixsrc = smrow ? smrow[r*W4+xx] : (r*W4+xx);
      float2 v = make_float2(0.f,0.f);
      if (pixsrc >= 0) v = *(const float2*)(src + (size_t)pixsrc*FL + choff);
      #pragma unroll
      for(int dd=0; dd<5; ++dd){
        int x = xx + 2 - dd;
        if (x>=0 && x<24){
          if (u0) acc[0][x] += v.x*wA[dy0*5+dd] + v.y*wB[dy0*5+dd];
          if (u1) acc[1][x] += v.x*wA[dy1*5+dd] + v.y*wB[dy1*5+dd];
        }
      }
    }
  }
  float bias = dw_b[i];
  #pragma unroll
  for(int x=0;x<24;x++){ acc[0][x]+=bias; acc[1][x]+=bias; }
  __shared__ float lds[256*25];
  __shared__ float smean[24], srstd[24];
  float gi = ln_w[i], bi = ln_b[i];
  #pragma unroll
  for(int yy=0; yy<2; ++yy){
    int y = y0 + yy;
    #pragma unroll
    for(int x=0;x<24;x++) lds[i*25+x]=acc[yy][x];
    __syncthreads();
    if (i<24){
      float s=0.f,s2=0.f;
      for(int j=0;j<256;j++){ float v=lds[j*25+i]; s+=v; s2+=v*v; }
      float mean = s*(1.0f/256.0f);
      float var = s2*(1.0f/256.0f) - mean*mean;
      smean[i]=mean; srstd[i]=rsqrtf(var+1e-5f);
    }
    __syncthreads();
    #pragma unroll
    for(int x=0;x<24;x++){
      float v = (acc[yy][x]-smean[x])*srstd[x]*gi + bi;
      float ge = 0.5f*v*(1.0f + erff(v*0.70710678118654752f));
      lds[i*25+x] = ge;
    }
    __syncthreads();
    if (i<24){
      float d0=0.f,d1=0.f;
      for(int j=0;j<256;j++){ float v=lds[j*25+i]; d0 += v*pw_w[j]; d1 += v*pw_w[256+j]; }
      float off0 = tanhf(d0)*(2.0f/24.0f);
      float off1 = tanhf(d1)*(2.0f/24.0f);
      float ry = (((float)y + 0.5f)/24.0f)*2.0f - 1.0f;
      float rx = (((float)i + 0.5f)/24.0f)*2.0f - 1.0f;
      float posy = off0 + ry, posx = off1 + rx;
      float px = ((posx + 1.0f)*0.5f)*23.0f;  // grid2[...,0] = x
      float py = ((posy + 1.0f)*0.5f)*23.0f;  // grid2[...,1] = y
      *(float2*)(grid2 + ((size_t)b*FN + y*W4 + i)*2) = make_float2(px, py);
    }
    __syncthreads();
  }
}

// ---------------- K5: correlation + max/argmax over t ---------------------
// XCD-swizzled: each XCD owns a 3-row band of both images across all t
__global__ __launch_bounds__(256) void k_corr(const float* __restrict__ cf,
    const float* __restrict__ idxT, const int* __restrict__ smap,
    const float* __restrict__ grid2,
    float* __restrict__ cors, int* __restrict__ cori){
  int i0 = blockIdx.x;            // 1152
  int band = i0 & 7; int k0 = i0 >> 3;   // k0 in [0,144)
  int ni = k0/72; int r0 = k0%72;
  int y = band*3 + r0/24; int xx = r0%24;
  int l = y*24 + xx;
  int blk = ni*FN + l;
  int tid = threadIdx.x;
  int g = tid>>6;
  float4 cfv = ((const float4*)(cf + (size_t)blk*FL))[tid];
  __shared__ float red[4];
  float best=-3.4e38f; int bidx=0;
  for(int ti=0; ti<TT; ++ti){
    int nt = ni*TT+ti;
    float2 gr = *(const float2*)(grid2 + ((size_t)(ni*48 + ti*4 + g)*FN + l)*2);
    float x0f = floorf(gr.x), y0f = floorf(gr.y);
    float wx = gr.x - x0f, wy = gr.y - y0f;
    float partial = 0.f;
    #pragma unroll
    for(int tap=0; tap<4; ++tap){
      float xf = x0f + (float)(tap&1);
      float yf = y0f + (float)(tap>>1);
      float w = ((tap&1)? wx : 1.f-wx) * ((tap>>1)? wy : 1.f-wy);
      if (xf>=0.f && xf<24.f && yf>=0.f && yf<24.f){
        int xi=(int)xf, yi=(int)yf;
        int sp2 = smap[nt*FN + yi*W4+xi];
        if (sp2 >= 0){
          float4 tv = ((const float4*)(idxT + (size_t)(nt*FN + sp2)*FL))[tid];
          partial += w*(tv.x*cfv.x + tv.y*cfv.y + tv.z*cfv.z + tv.w*cfv.w);
        }
      }
    }
    for(int o=32;o>0;o>>=1) partial += __shfl_down(partial, o, 64);
    if ((tid&63)==0) red[tid>>6]=partial;
    __syncthreads();
    if (tid==0){
      float s = red[0]+red[1]+red[2]+red[3];
      if (s > best){ best=s; bidx=ti; }
    }
    __syncthreads();
  }
  if (tid==0){ cors[blk]=best; cori[blk]=bidx; }
}

// ---------------- K6: gather winning frame -> fcat (pixel-major bf16) -----
__global__ __launch_bounds__(256) void k_gather(const float* __restrict__ s1,
    const float* __restrict__ s2, const float* __restrict__ s3,
    const unsigned short* __restrict__ sT, int use_t,
    const int* __restrict__ smap, const float* __restrict__ grid2,
    const int* __restrict__ cori, unsigned short* __restrict__ fcat){
  int blk = blockIdx.x; int ni = blk/FN, l = blk%FN;
  int tid = threadIdx.x;
  int g = tid>>6;
  int ts = cori[blk];
  int nt = ni*TT + ts;
  float2 gr = *(const float2*)(grid2 + ((size_t)(ni*48 + ts*4 + g)*FN + l)*2);
  float x0f = floorf(gr.x), y0f = floorf(gr.y);
  float wx = gr.x - x0f, wy = gr.y - y0f;
  int sp[4]; float wt[4];
  #pragma unroll
  for(int tap=0; tap<4; ++tap){
    float xf = x0f + (float)(tap&1), yf = y0f + (float)(tap>>1);
    float w = ((tap&1)? wx : 1.f-wx)*((tap>>1)? wy : 1.f-wy);
    bool v = (xf>=0.f && xf<24.f && yf>=0.f && yf<24.f);
    int xi=(int)xf, yi=(int)yf;
    int pp = v ? smap[nt*FN + yi*W4+xi] : -1;
    sp[tap] = (pp>=0)? pp : 0; wt[tap] = (v && pp>=0)? w : 0.f;
  }
  float a[3][4];
  #pragma unroll
  for(int t2=0;t2<3;t2++){ a[t2][0]=0.f;a[t2][1]=0.f;a[t2][2]=0.f;a[t2][3]=0.f; }
  if (use_t){
    #pragma unroll
    for(int tap=0;tap<4;++tap){
      float w = wt[tap];
      if (w != 0.f){
        #pragma unroll
        for(int t2=0;t2<3;t2++){
          const unsigned short* p = sT + ((size_t)(t2*NN*TT + nt)*FN + sp[tap])*FL + tid*4;
          ushort4 r = *(const ushort4*)p;
          a[t2][0] += w*u2f(r.x); a[t2][1] += w*u2f(r.y);
          a[t2][2] += w*u2f(r.z); a[t2][3] += w*u2f(r.w);
        }
      }
    }
  } else {
    size_t chbase = ((size_t)nt*FL + tid*4)*FN;
    const float* sa[3] = { s1+chbase, s2+chbase, s3+chbase };
    #pragma unroll
    for(int t2=0;t2<3;t2++){
      #pragma unroll
      for(int tap=0;tap<4;++tap){
        float w = wt[tap];
        if (w != 0.f){
          const float* p = sa[t2] + sp[tap];
          a[t2][0] += w*p[0]; a[t2][1] += w*p[FN];
          a[t2][2] += w*p[2*FN]; a[t2][3] += w*p[3*FN];
        }
      }
    }
  }
  // LDS bounce: cl = ci*16+subpix  ->  [tens][subpix][ci] (padded 65)
  __shared__ float ldsv[3*16*65];
  #pragma unroll
  for(int t2=0;t2<3;t2++){
    #pragma unroll
    for(int k=0;k<4;k++){
      int cl = tid*4 + k;
      ldsv[t2*1040 + (cl&15)*65 + (cl>>4)] = a[t2][k];
    }
  }
  __syncthreads();
  int by = l/W4, bx = l%W4;
  int subpix = tid>>4, j = tid&15;
  int sy = subpix>>2, sx = subpix&3;
  unsigned short tmp[12];
  #pragma unroll
  for(int kk=0;kk<12;kk++){
    int ch = j*12+kk; int t2 = ch>>6; int ci = ch&63;
    tmp[kk] = f2u(ldsv[t2*1040 + subpix*65 + ci]);
  }
  unsigned short* dst = fcat + (((size_t)(ni*HH + by*4+sy))*WW + bx*4+sx)*192 + j*12;
  uint2* d2 = (uint2*)dst;
  d2[0] = make_uint2((unsigned)tmp[0] | ((unsigned)tmp[1]<<16), (unsigned)tmp[2] | ((unsigned)tmp[3]<<16));
  d2[1] = make_uint2((unsigned)tmp[4] | ((unsigned)tmp[5]<<16), (unsigned)tmp[6] | ((unsigned)tmp[7]<<16));
  d2[2] = make_uint2((unsigned)tmp[8] | ((unsigned)tmp[9]<<16), (unsigned)tmp[10]| ((unsigned)tmp[11]<<16));
}

// ---------------- K7: fusion conv via MFMA (implicit GEMM) + epilogue -----
__global__ __launch_bounds__(256) void k_fusion_mfma(
    const unsigned short* __restrict__ fcat, const unsigned short* __restrict__ wpk,
    const float* __restrict__ fb, const float* __restrict__ cors,
    const float* __restrict__ anchor, float* __restrict__ out){
  int b = blockIdx.x;             // ni*288 + y*3 + xb
  int ni = b/288; int rem = b%288; int y = rem/3, xb = rem%3; int x0 = xb*32;
  int tid = threadIdx.x;
  __shared__ __align__(16) char sbuf[40960];
  unsigned short* aT = (unsigned short*)sbuf;   // [3 rows][34 x][200 ci-padded]
  // ---- stage A tile (zero-padded borders) ----
  for (int i = tid; i < 3*34*48; i += 256){
    int ch4 = i % 48; int t2 = i / 48;
    int xx = t2 % 34; int rr = t2 / 34;
    int row = y - 1 + rr, sx = x0 - 1 + xx;
    uint2 v = make_uint2(0u, 0u);
    if (row >= 0 && row < HH && sx >= 0 && sx < WW)
      v = *(const uint2*)(fcat + (((size_t)(ni*HH + row))*WW + sx)*192 + ch4*4);
    *(uint2*)(aT + ((size_t)rr*34 + xx)*200 + ch4*4) = v;
  }
  __syncthreads();
  int wv = tid>>6, lane = tid&63;
  int mt = wv&1, np = wv>>1;
  int m = lane&15, quad = lane>>4;
  f32x4 c0 = {0.f,0.f,0.f,0.f}, c1 = {0.f,0.f,0.f,0.f};
  for (int tap=0; tap<9; ++tap){
    int dy = tap/3, dx = tap%3;
    const unsigned short* arow = aT + ((size_t)dy*34 + mt*16 + m + dx)*200 + quad*8;
    #pragma unroll
    for (int kc=0; kc<6; ++kc){
      short8 af = *(const short8*)(arow + kc*32);
      const unsigned short* bp = wpk + (size_t)((tap*6+kc)*4 + np*2)*512 + lane*8;
      short8 b0 = *(const short8*)(bp);
      short8 b1 = *(const short8*)(bp + 512);
      c0 = __builtin_amdgcn_mfma_f32_16x16x32_bf16(af, b0, c0, 0, 0, 0);
      c1 = __builtin_amdgcn_mfma_f32_16x16x32_bf16(af, b1, c1, 0, 0, 0);
    }
  }
  __syncthreads();                 // done reading aT; reuse LDS
  float* oT = (float*)sbuf;        // [32 x][65 pad] holding co 0..63
  #pragma unroll
  for (int r=0; r<4; ++r){
    int xl = mt*16 + quad*4 + r;
    oT[xl*65 + np*32 + m]      = c0[r];
    oT[xl*65 + np*32 + 16 + m] = c1[r];
  }
  __syncthreads();
  for (int i = tid; i < 2048; i += 256){
    int co = i >> 5, xl = i & 31;
    int x = x0 + xl;
    float csm = cors[ni*FN + (y>>2)*W4 + (x>>2)];
    size_t oidx = ((size_t)(ni*CC + co)*HH + y)*WW + x;
    out[oidx] = (oT[xl*65 + co] + fb[co])*csm + anchor[oidx];
  }
}

// --------------------------------------------------------------------------
extern "C" void kernel_launch(void* const* d_in, const int* in_sizes, int n_in,
                              void* d_out, int out_size, void* d_ws, size_t ws_size,
                              hipStream_t stream) {
  const float* curr   = (const float*)d_in[0];
  const float* idxf   = (const float*)d_in[1];
  const float* anchor = (const float*)d_in[2];
  const float* s1 = (const float*)d_in[3];
  const float* s2 = (const float*)d_in[4];
  const float* s3 = (const float*)d_in[5];
  const float* loc = (const float*)d_in[6];
  const float* fw  = (const float*)d_in[7];
  const float* fb  = (const float*)d_in[8];
  const float* dww = (const float*)d_in[9];
  const float* dwb = (const float*)d_in[10];
  const float* lnw = (const float*)d_in[11];
  const float* lnb = (const float*)d_in[12];
  const float* pww = (const float*)d_in[13];
  char* ws = (char*)d_ws;
  const size_t MB = 1024*1024;
  int*            smap  = (int*)           (ws + 0);       //    55,296 B
  float*          nrm   = (float*)         (ws + 1*MB);    //    55,296 B
  float*          part  = (float*)         (ws + 2*MB);    //   884,736 B
  float*          cf    = (float*)         (ws + 3*MB);    // 4,718,592 B
  float*          idxT  = (float*)         (ws + 8*MB);    // 56,623,104 B
  float*          grid2 = (float*)         (ws + 62*MB);   //   442,368 B
  float*          cors  = (float*)         (ws + 63*MB);   //     4,608 B
  int*            cori  = (int*)           (ws + 63*MB + 8192);
  unsigned short* fcat  = (unsigned short*)(ws + 64*MB);   // 7,077,888 B
  unsigned short* wpk   = (unsigned short*)(ws + 71*MB);   //   221,184 B
  unsigned short* sT    = (unsigned short*)(ws + 72*MB);   // 84,934,656 B (optional)
  int use_t = (ws_size >= (size_t)(72*MB) + 84934656u) ? 1 : 0;
  float* out = (float*)d_out;

  k_map   <<<54,    256, 0, stream>>>(loc, smap);
  k_part  <<<384,   576, 0, stream>>>(idxf, part);
  k_norm  <<<54,    256, 0, stream>>>(part, nrm);
  k_cf    <<<1152,  256, 0, stream>>>(curr, cf);
  k_tr_idx<<<3456,  256, 0, stream>>>(idxf, nrm, idxT);
  if (use_t)
    k_tr_s<<<10368, 256, 0, stream>>>(s1, s2, s3, sT);
  k_wpack <<<432,   256, 0, stream>>>(fw, wpk);
  k_offnet<<<1152,  256, 0, stream>>>(cf, idxT, smap, dww, dwb, lnw, lnb, pww, grid2);
  k_corr  <<<1152,  256, 0, stream>>>(cf, idxT, smap, grid2, cors, cori);
  k_gather<<<1152,  256, 0, stream>>>(s1, s2, s3, sT, use_t, smap, grid2, cori, fcat);
  k_fusion_mfma<<<576, 256, 0, stream>>>(fcat, wpk, fb, cors, anchor, out);
}

// Round 5
// 529.854 us; speedup vs baseline: 1.0536x; 1.0536x over previous
//
#include <hip/hip_runtime.h>
#include <hip/hip_bf16.h>
#include <math.h>

// Problem constants (n=2, t=12, h=w=96, c=64)
#define NN 2
#define TT 12
#define HH 96
#define WW 96
#define CC 64
#define H4 24
#define W4 24
#define FL 1024   // feat_len = c*16
#define FN 576    // H4*W4

typedef short short8 __attribute__((ext_vector_type(8)));
typedef float f32x4 __attribute__((ext_vector_type(4)));

__device__ __forceinline__ float u2f(unsigned short u){
  unsigned int x = ((unsigned int)u)<<16; float f; __builtin_memcpy(&f,&x,4); return f;
}
__device__ __forceinline__ unsigned short f2u(float f){
  __hip_bfloat16 b = __float2bfloat16(f); unsigned short u; __builtin_memcpy(&u,&b,2); return u;
}

// ---------------- K0: nearest-neighbor source map -------------------------
__global__ void k_map(const float* __restrict__ loc, int* __restrict__ smap){
  int i = blockIdx.x*256 + threadIdx.x;
  if (i >= NN*TT*FN) return;
  int nt = i / FN, pix = i % FN;
  int ni = nt / TT, ti = nt % TT;
  const float* lp = loc + ((size_t)ni*(2*TT) + 2*ti)*FN + pix;
  float vx = lp[0];
  float vy = lp[FN];
  // EXACT replication of reference f32 arithmetic:
  float gx = (2.0f*vx)/23.0f - 1.0f;
  float gy = (2.0f*vy)/23.0f - 1.0f;
  float x = ((gx + 1.0f)*0.5f)*23.0f;
  float y = ((gy + 1.0f)*0.5f)*23.0f;
  int xi = (int)rintf(x);
  int yi = (int)rintf(y);
  bool valid = (xi>=0)&&(xi<W4)&&(yi>=0)&&(yi<H4);
  smap[i] = valid ? (yi*W4+xi) : -1;
}

// ---------------- K1: per-source-pixel L2 norms (coalesced) ---------------
__global__ void k_part(const float* __restrict__ idxf, float* __restrict__ part){
  int blk = blockIdx.x;           // nt*16 + chunk
  int nt = blk >> 4, ch0 = (blk & 15)*64;
  int pix = threadIdx.x;          // 576 threads
  const float* p = idxf + ((size_t)nt*FL + ch0)*FN + pix;
  float s = 0.f;
  for (int c=0;c<64;c++){ float v = p[(size_t)c*FN]; s += v*v; }
  part[(size_t)blk*FN + pix] = s;
}
__global__ void k_norm(const float* __restrict__ part, float* __restrict__ nrm){
  int i = blockIdx.x*256+threadIdx.x;
  if (i>=NN*TT*FN) return;
  int nt = i/FN, pix = i%FN;
  float s=0.f;
  for (int c=0;c<16;c++) s += part[(size_t)(nt*16+c)*FN + pix];
  nrm[i] = sqrtf(s);
}

// ---------------- K2: normalized unfolded query cf[n][l][1024] ------------
__global__ void k_cf(const float* __restrict__ curr, float* __restrict__ cf){
  int blk = blockIdx.x;           // n*576 + l
  int ni = blk/FN, l = blk%FN;
  int by = l/W4, bx = l%W4;
  int tid = threadIdx.x;
  int ci = tid>>2, sy = tid&3;
  const float* p = curr + (((size_t)ni*CC+ci)*HH + by*4+sy)*WW + bx*4;
  float4 v = *(const float4*)p;
  float s = v.x*v.x+v.y*v.y+v.z*v.z+v.w*v.w;
  __shared__ float red[256];
  red[tid]=s; __syncthreads();
  for(int o=128;o>0;o>>=1){ if(tid<o) red[tid]+=red[tid+o]; __syncthreads(); }
  float r = 1.0f/fmaxf(sqrtf(red[0]),1e-12f);
  float4 o4 = make_float4(v.x*r, v.y*r, v.z*r, v.w*r);
  ((float4*)(cf + (size_t)blk*FL))[tid] = o4;
}

// ---------------- K3a: transpose+normalize idxf -> idxT [nt][pix][1024] ---
__global__ __launch_bounds__(256) void k_tr_idx(const float* __restrict__ idxf,
    const float* __restrict__ nrm, float* __restrict__ idxT){
  int b = blockIdx.x;             // ((nt*9 + pixt)*16 + cht)
  int cht = b & 15; int b2 = b >> 4;
  int pixt = b2 % 9; int nt = b2 / 9;
  int tid = threadIdx.x;
  __shared__ float t[64][65];
  #pragma unroll
  for (int r=0; r<16; ++r){
    int ch_l = r*4 + (tid>>6), pix_l = tid & 63;
    t[ch_l][pix_l] = idxf[((size_t)nt*FL + cht*64 + ch_l)*FN + pixt*64 + pix_l];
  }
  __syncthreads();
  #pragma unroll
  for (int r=0; r<16; ++r){
    int pix_l = r*4 + (tid>>6), ch_l = tid & 63;
    int gpix = pixt*64 + pix_l;
    float inv = 1.0f/fmaxf(nrm[nt*FN + gpix], 1e-12f);
    idxT[((size_t)nt*FN + gpix)*FL + cht*64 + ch_l] = t[ch_l][pix_l]*inv;
  }
}

// ---------------- K3b: transpose s1/s2/s3 -> bf16 sT [tens][nt][pix][1024]-
__global__ __launch_bounds__(256) void k_tr_s(const float* __restrict__ s1,
    const float* __restrict__ s2, const float* __restrict__ s3,
    unsigned short* __restrict__ sT){
  int b = blockIdx.x;             // tens*3456 + ((nt*9+pixt)*16+cht)
  int tens = b / 3456; int bb = b % 3456;
  int cht = bb & 15; int b2 = bb >> 4;
  int pixt = b2 % 9; int nt = b2 / 9;
  const float* src = (tens==0)? s1 : (tens==1)? s2 : s3;
  int tid = threadIdx.x;
  __shared__ float t[64][65];
  #pragma unroll
  for (int r=0; r<16; ++r){
    int ch_l = r*4 + (tid>>6), pix_l = tid & 63;
    t[ch_l][pix_l] = src[((size_t)nt*FL + cht*64 + ch_l)*FN + pixt*64 + pix_l];
  }
  __syncthreads();
  #pragma unroll
  for (int r=0; r<16; ++r){
    int pix_l = r*4 + (tid>>6), ch_l = tid & 63;
    int gpix = pixt*64 + pix_l;
    sT[((size_t)(tens*NN*TT + nt)*FN + gpix)*FL + cht*64 + ch_l] = f2u(t[ch_l][pix_l]);
  }
}

// ---------------- K3c: prepack fusion weights in MFMA B-fragment order ----
__global__ void k_wpack(const float* __restrict__ fw, unsigned short* __restrict__ wp){
  int idx = blockIdx.x*256 + threadIdx.x;
  if (idx >= 9*6*4*64*8) return;
  int j = idx & 7; int t2 = idx >> 3;
  int L = t2 & 63; int t3 = t2 >> 6;
  int ntl = t3 & 3; int t4 = t3 >> 2;
  int kc = t4 % 6; int tap = t4 / 6;
  int dy = tap/3, dx = tap%3;
  int n = ntl*16 + (L & 15);
  int quad = L >> 4;
  int k = kc*32 + quad*8 + j;     // ci in [0,192)
  wp[idx] = f2u(fw[((size_t)n*192 + k)*9 + dy*3 + dx]);
}

// ---------------- K4: fused offset network -> grid2 (pixel coords) --------
// 2 output rows per block; XCD-swizzled; NO-SPILL (launch_bounds 256,2) +
// parallel segmented reductions for LN stats and pw dots.
__global__ __launch_bounds__(256, 2) void k_offnet(
    const float* __restrict__ cf, const float* __restrict__ idxT,
    const int* __restrict__ smap,
    const float* __restrict__ dw_w, const float* __restrict__ dw_b,
    const float* __restrict__ ln_w, const float* __restrict__ ln_b,
    const float* __restrict__ pw_w, float* __restrict__ grid2){
  int i0 = blockIdx.x;            // 1152 = 96 b x 12 ybands
  int xcd = i0 & 7; int kk = i0 >> 3;   // kk in [0,144)
  int b = (kk/12)*8 + xcd;              // [0,96): all 12 bands of b on one XCD
  int y0 = 2*(kk%12);
  int i = threadIdx.x;

  __shared__ float smat[256][25];       // acc matrix, then ge matrix
  __shared__ float spart[2][10][24];    // segment partials (reused)
  __shared__ float sstat[2][24];        // mean, rstd
  __shared__ float pw0s[256], pw1s[256];

  pw0s[i] = pw_w[i]; pw1s[i] = pw_w[256+i];

  float wA[25], wB[25];
  const float* wp = dw_w + (size_t)i*50;
  #pragma unroll
  for(int k=0;k<25;k++){ wA[k]=wp[k]; wB[k]=wp[25+k]; }
  const float* src; int choff; const int* smrow;
  if (i < 128){                   // q part: tile ordering (rep, n, g)
    int n2 = (b>>2)&1, g2 = b&3;
    src = cf + (size_t)n2*FN*FL;
    choff = g2*256 + 2*i;
    smrow = nullptr;
  } else {                        // k part: ordering (n, t, g)
    int nk = b/48, tik = (b>>2)%12, gk = b&3;
    int nt = nk*TT + tik;
    src = idxT + (size_t)nt*FN*FL;
    choff = gk*256 + 2*(i-128);
    smrow = smap + nt*FN;
  }
  float acc[2][24];
  #pragma unroll
  for(int x=0;x<24;x++){ acc[0][x]=0.f; acc[1][x]=0.f; }
  #pragma unroll
  for(int rr=0; rr<6; ++rr){      // rr static -> all weight indices static
    int r = y0 - 2 + rr;
    if (r >= 0 && r < H4){
      #pragma unroll
      for(int xx=0; xx<24; ++xx){
        int pixsrc = smrow ? smrow[r*W4+xx] : (r*W4+xx);
        float2 v = make_float2(0.f,0.f);
        if (pixsrc >= 0) v = *(const float2*)(src + (size_t)pixsrc*FL + choff);
        #pragma unroll
        for(int dd=0; dd<5; ++dd){
          int x = xx + 2 - dd;
          if (x>=0 && x<24){
            if (rr < 5) acc[0][x] += v.x*wA[rr*5+dd]     + v.y*wB[rr*5+dd];
            if (rr >= 1) acc[1][x] += v.x*wA[(rr-1)*5+dd] + v.y*wB[(rr-1)*5+dd];
          }
        }
      }
    }
  }
  float bias = dw_b[i];
  #pragma unroll
  for(int x=0;x<24;x++){ acc[0][x]+=bias; acc[1][x]+=bias; }
  float gi = ln_w[i], bi = ln_b[i];

  for(int yy=0; yy<2; ++yy){
    int y = y0 + yy;
    // 1) stage acc row to LDS
    #pragma unroll
    for(int x=0;x<24;x++) smat[i][x] = acc[yy][x];
    __syncthreads();
    // 2) segmented sums over the 256 channels (240 threads active)
    if (i < 240){
      int x = i % 24, seg = i / 24;
      int j0 = seg*26, j1 = (seg==9)? 256 : (j0+26);
      float s=0.f, s2=0.f;
      for(int j=j0;j<j1;++j){ float v=smat[j][x]; s+=v; s2+=v*v; }
      spart[0][seg][x]=s; spart[1][seg][x]=s2;
    }
    __syncthreads();
    // 3) finalize stats
    if (i < 24){
      float s=0.f,s2=0.f;
      #pragma unroll
      for(int g2=0;g2<10;g2++){ s+=spart[0][g2][i]; s2+=spart[1][g2][i]; }
      float mean = s*(1.0f/256.0f);
      float var  = s2*(1.0f/256.0f) - mean*mean;
      sstat[0][i]=mean; sstat[1][i]=rsqrtf(var+1e-5f);
    }
    __syncthreads();
    // 4) LN + GELU -> overwrite smat with ge
    #pragma unroll
    for(int x=0;x<24;x++){
      float v = (acc[yy][x]-sstat[0][x])*sstat[1][x]*gi + bi;
      float ge = 0.5f*v*(1.0f + erff(v*0.70710678118654752f));
      smat[i][x] = ge;
    }
    __syncthreads();
    // 5) segmented pw dots
    if (i < 240){
      int x = i % 24, seg = i / 24;
      int j0 = seg*26, j1 = (seg==9)? 256 : (j0+26);
      float d0=0.f, d1=0.f;
      for(int j=j0;j<j1;++j){ float v=smat[j][x]; d0+=v*pw0s[j]; d1+=v*pw1s[j]; }
      spart[0][seg][x]=d0; spart[1][seg][x]=d1;
    }
    __syncthreads();
    // 6) finalize + emit grid
    if (i < 24){
      float d0=0.f,d1=0.f;
      #pragma unroll
      for(int g2=0;g2<10;g2++){ d0+=spart[0][g2][i]; d1+=spart[1][g2][i]; }
      float off0 = tanhf(d0)*(2.0f/24.0f);
      float off1 = tanhf(d1)*(2.0f/24.0f);
      float ry = (((float)y + 0.5f)/24.0f)*2.0f - 1.0f;
      float rx = (((float)i + 0.5f)/24.0f)*2.0f - 1.0f;
      float posy = off0 + ry, posx = off1 + rx;
      float px = ((posx + 1.0f)*0.5f)*23.0f;  // grid2[...,0] = x
      float py = ((posy + 1.0f)*0.5f)*23.0f;  // grid2[...,1] = y
      *(float2*)(grid2 + ((size_t)b*FN + y*W4 + i)*2) = make_float2(px, py);
    }
    __syncthreads();
  }
}

// ---------------- K5: correlation + max/argmax over t ---------------------
// XCD-swizzled: each XCD owns a 3-row band of both images across all t
__global__ __launch_bounds__(256) void k_corr(const float* __restrict__ cf,
    const float* __restrict__ idxT, const int* __restrict__ smap,
    const float* __restrict__ grid2,
    float* __restrict__ cors, int* __restrict__ cori){
  int i0 = blockIdx.x;            // 1152
  int band = i0 & 7; int k0 = i0 >> 3;   // k0 in [0,144)
  int ni = k0/72; int r0 = k0%72;
  int y = band*3 + r0/24; int xx = r0%24;
  int l = y*24 + xx;
  int blk = ni*FN + l;
  int tid = threadIdx.x;
  int g = tid>>6;
  float4 cfv = ((const float4*)(cf + (size_t)blk*FL))[tid];
  __shared__ float red[4];
  float best=-3.4e38f; int bidx=0;
  for(int ti=0; ti<TT; ++ti){
    int nt = ni*TT+ti;
    float2 gr = *(const float2*)(grid2 + ((size_t)(ni*48 + ti*4 + g)*FN + l)*2);
    float x0f = floorf(gr.x), y0f = floorf(gr.y);
    float wx = gr.x - x0f, wy = gr.y - y0f;
    float partial = 0.f;
    #pragma unroll
    for(int tap=0; tap<4; ++tap){
      float xf = x0f + (float)(tap&1);
      float yf = y0f + (float)(tap>>1);
      float w = ((tap&1)? wx : 1.f-wx) * ((tap>>1)? wy : 1.f-wy);
      if (xf>=0.f && xf<24.f && yf>=0.f && yf<24.f){
        int xi=(int)xf, yi=(int)yf;
        int sp2 = smap[nt*FN + yi*W4+xi];
        if (sp2 >= 0){
          float4 tv = ((const float4*)(idxT + (size_t)(nt*FN + sp2)*FL))[tid];
          partial += w*(tv.x*cfv.x + tv.y*cfv.y + tv.z*cfv.z + tv.w*cfv.w);
        }
      }
    }
    for(int o=32;o>0;o>>=1) partial += __shfl_down(partial, o, 64);
    if ((tid&63)==0) red[tid>>6]=partial;
    __syncthreads();
    if (tid==0){
      float s = red[0]+red[1]+red[2]+red[3];
      if (s > best){ best=s; bidx=ti; }
    }
    __syncthreads();
  }
  if (tid==0){ cors[blk]=best; cori[blk]=bidx; }
}

// ---------------- K6: gather winning frame -> fcat (pixel-major bf16) -----
__global__ __launch_bounds__(256) void k_gather(const float* __restrict__ s1,
    const float* __restrict__ s2, const float* __restrict__ s3,
    const unsigned short* __restrict__ sT, int use_t,
    const int* __restrict__ smap, const float* __restrict__ grid2,
    const int* __restrict__ cori, unsigned short* __restrict__ fcat){
  int blk = blockIdx.x; int ni = blk/FN, l = blk%FN;
  int tid = threadIdx.x;
  int g = tid>>6;
  int ts = cori[blk];
  int nt = ni*TT + ts;
  float2 gr = *(const float2*)(grid2 + ((size_t)(ni*48 + ts*4 + g)*FN + l)*2);
  float x0f = floorf(gr.x), y0f = floorf(gr.y);
  float wx = gr.x - x0f, wy = gr.y - y0f;
  int sp[4]; float wt[4];
  #pragma unroll
  for(int tap=0; tap<4; ++tap){
    float xf = x0f + (float)(tap&1), yf = y0f + (float)(tap>>1);
    float w = ((tap&1)? wx : 1.f-wx)*((tap>>1)? wy : 1.f-wy);
    bool v = (xf>=0.f && xf<24.f && yf>=0.f && yf<24.f);
    int xi=(int)xf, yi=(int)yf;
    int pp = v ? smap[nt*FN + yi*W4+xi] : -1;
    sp[tap] = (pp>=0)? pp : 0; wt[tap] = (v && pp>=0)? w : 0.f;
  }
  float a[3][4];
  #pragma unroll
  for(int t2=0;t2<3;t2++){ a[t2][0]=0.f;a[t2][1]=0.f;a[t2][2]=0.f;a[t2][3]=0.f; }
  if (use_t){
    #pragma unroll
    for(int tap=0;tap<4;++tap){
      float w = wt[tap];
      if (w != 0.f){
        #pragma unroll
        for(int t2=0;t2<3;t2++){
          const unsigned short* p = sT + ((size_t)(t2*NN*TT + nt)*FN + sp[tap])*FL + tid*4;
          ushort4 r = *(const ushort4*)p;
          a[t2][0] += w*u2f(r.x); a[t2][1] += w*u2f(r.y);
          a[t2][2] += w*u2f(r.z); a[t2][3] += w*u2f(r.w);
        }
      }
    }
  } else {
    size_t chbase = ((size_t)nt*FL + tid*4)*FN;
    const float* sa[3] = { s1+chbase, s2+chbase, s3+chbase };
    #pragma unroll
    for(int t2=0;t2<3;t2++){
      #pragma unroll
      for(int tap=0;tap<4;++tap){
        float w = wt[tap];
        if (w != 0.f){
          const float* p = sa[t2] + sp[tap];
          a[t2][0] += w*p[0]; a[t2][1] += w*p[FN];
          a[t2][2] += w*p[2*FN]; a[t2][3] += w*p[3*FN];
        }
      }
    }
  }
  // LDS bounce: cl = ci*16+subpix  ->  [tens][subpix][ci] (padded 65)
  __shared__ float ldsv[3*16*65];
  #pragma unroll
  for(int t2=0;t2<3;t2++){
    #pragma unroll
    for(int k=0;k<4;k++){
      int cl = tid*4 + k;
      ldsv[t2*1040 + (cl&15)*65 + (cl>>4)] = a[t2][k];
    }
  }
  __syncthreads();
  int by = l/W4, bx = l%W4;
  int subpix = tid>>4, j = tid&15;
  int sy = subpix>>2, sx = subpix&3;
  unsigned short tmp[12];
  #pragma unroll
  for(int kk=0;kk<12;kk++){
    int ch = j*12+kk; int t2 = ch>>6; int ci = ch&63;
    tmp[kk] = f2u(ldsv[t2*1040 + subpix*65 + ci]);
  }
  unsigned short* dst = fcat + (((size_t)(ni*HH + by*4+sy))*WW + bx*4+sx)*192 + j*12;
  uint2* d2 = (uint2*)dst;
  d2[0] = make_uint2((unsigned)tmp[0] | ((unsigned)tmp[1]<<16), (unsigned)tmp[2] | ((unsigned)tmp[3]<<16));
  d2[1] = make_uint2((unsigned)tmp[4] | ((unsigned)tmp[5]<<16), (unsigned)tmp[6] | ((unsigned)tmp[7]<<16));
  d2[2] = make_uint2((unsigned)tmp[8] | ((unsigned)tmp[9]<<16), (unsigned)tmp[10]| ((unsigned)tmp[11]<<16));
}

// ---------------- K7: fusion conv via MFMA (implicit GEMM) + epilogue -----
__global__ __launch_bounds__(256) void k_fusion_mfma(
    const unsigned short* __restrict__ fcat, const unsigned short* __restrict__ wpk,
    const float* __restrict__ fb, const float* __restrict__ cors,
    const float* __restrict__ anchor, float* __restrict__ out){
  int b = blockIdx.x;             // ni*288 + y*3 + xb
  int ni = b/288; int rem = b%288; int y = rem/3, xb = rem%3; int x0 = xb*32;
  int tid = threadIdx.x;
  __shared__ __align__(16) char sbuf[40960];
  unsigned short* aT = (unsigned short*)sbuf;   // [3 rows][34 x][200 ci-padded]
  // ---- stage A tile (zero-padded borders) ----
  for (int i = tid; i < 3*34*48; i += 256){
    int ch4 = i % 48; int t2 = i / 48;
    int xx = t2 % 34; int rr = t2 / 34;
    int row = y - 1 + rr, sx = x0 - 1 + xx;
    uint2 v = make_uint2(0u, 0u);
    if (row >= 0 && row < HH && sx >= 0 && sx < WW)
      v = *(const uint2*)(fcat + (((size_t)(ni*HH + row))*WW + sx)*192 + ch4*4);
    *(uint2*)(aT + ((size_t)rr*34 + xx)*200 + ch4*4) = v;
  }
  __syncthreads();
  int wv = tid>>6, lane = tid&63;
  int mt = wv&1, np = wv>>1;
  int m = lane&15, quad = lane>>4;
  f32x4 c0 = {0.f,0.f,0.f,0.f}, c1 = {0.f,0.f,0.f,0.f};
  for (int tap=0; tap<9; ++tap){
    int dy = tap/3, dx = tap%3;
    const unsigned short* arow = aT + ((size_t)dy*34 + mt*16 + m + dx)*200 + quad*8;
    #pragma unroll
    for (int kc=0; kc<6; ++kc){
      short8 af = *(const short8*)(arow + kc*32);
      const unsigned short* bp = wpk + (size_t)((tap*6+kc)*4 + np*2)*512 + lane*8;
      short8 b0 = *(const short8*)(bp);
      short8 b1 = *(const short8*)(bp + 512);
      c0 = __builtin_amdgcn_mfma_f32_16x16x32_bf16(af, b0, c0, 0, 0, 0);
      c1 = __builtin_amdgcn_mfma_f32_16x16x32_bf16(af, b1, c1, 0, 0, 0);
    }
  }
  __syncthreads();                 // done reading aT; reuse LDS
  float* oT = (float*)sbuf;        // [32 x][65 pad] holding co 0..63
  #pragma unroll
  for (int r=0; r<4; ++r){
    int xl = mt*16 + quad*4 + r;
    oT[xl*65 + np*32 + m]      = c0[r];
    oT[xl*65 + np*32 + 16 + m] = c1[r];
  }
  __syncthreads();
  for (int i = tid; i < 2048; i += 256){
    int co = i >> 5, xl = i & 31;
    int x = x0 + xl;
    float csm = cors[ni*FN + (y>>2)*W4 + (x>>2)];
    size_t oidx = ((size_t)(ni*CC + co)*HH + y)*WW + x;
    out[oidx] = (oT[xl*65 + co] + fb[co])*csm + anchor[oidx];
  }
}

// --------------------------------------------------------------------------
extern "C" void kernel_launch(void* const* d_in, const int* in_sizes, int n_in,
                              void* d_out, int out_size, void* d_ws, size_t ws_size,
                              hipStream_t stream) {
  const float* curr   = (const float*)d_in[0];
  const float* idxf   = (const float*)d_in[1];
  const float* anchor = (const float*)d_in[2];
  const float* s1 = (const float*)d_in[3];
  const float* s2 = (const float*)d_in[4];
  const float* s3 = (const float*)d_in[5];
  const float* loc = (const float*)d_in[6];
  const float* fw  = (const float*)d_in[7];
  const float* fb  = (const float*)d_in[8];
  const float* dww = (const float*)d_in[9];
  const float* dwb = (const float*)d_in[10];
  const float* lnw = (const float*)d_in[11];
  const float* lnb = (const float*)d_in[12];
  const float* pww = (const float*)d_in[13];
  char* ws = (char*)d_ws;
  const size_t MB = 1024*1024;
  int*            smap  = (int*)           (ws + 0);       //    55,296 B
  float*          nrm   = (float*)         (ws + 1*MB);    //    55,296 B
  float*          part  = (float*)         (ws + 2*MB);    //   884,736 B
  float*          cf    = (float*)         (ws + 3*MB);    // 4,718,592 B
  float*          idxT  = (float*)         (ws + 8*MB);    // 56,623,104 B
  float*          grid2 = (float*)         (ws + 62*MB);   //   442,368 B
  float*          cors  = (float*)         (ws + 63*MB);   //     4,608 B
  int*            cori  = (int*)           (ws + 63*MB + 8192);
  unsigned short* fcat  = (unsigned short*)(ws + 64*MB);   // 7,077,888 B
  unsigned short* wpk   = (unsigned short*)(ws + 71*MB);   //   221,184 B
  unsigned short* sT    = (unsigned short*)(ws + 72*MB);   // 84,934,656 B (optional)
  int use_t = (ws_size >= (size_t)(72*MB) + 84934656u) ? 1 : 0;
  float* out = (float*)d_out;

  k_map   <<<54,    256, 0, stream>>>(loc, smap);
  k_part  <<<384,   576, 0, stream>>>(idxf, part);
  k_norm  <<<54,    256, 0, stream>>>(part, nrm);
  k_cf    <<<1152,  256, 0, stream>>>(curr, cf);
  k_tr_idx<<<3456,  256, 0, stream>>>(idxf, nrm, idxT);
  if (use_t)
    k_tr_s<<<10368, 256, 0, stream>>>(s1, s2, s3, sT);
  k_wpack <<<432,   256, 0, stream>>>(fw, wpk);
  k_offnet<<<1152,  256, 0, stream>>>(cf, idxT, smap, dww, dwb, lnw, lnb, pww, grid2);
  k_corr  <<<1152,  256, 0, stream>>>(cf, idxT, smap, grid2, cors, cori);
  k_gather<<<1152,  256, 0, stream>>>(s1, s2, s3, sT, use_t, smap, grid2, cori, fcat);
  k_fusion_mfma<<<576, 256, 0, stream>>>(fcat, wpk, fb, cors, anchor, out);
}